// Round 18
// baseline (735.348 us; speedup 1.0000x reference)
//
#include <hip/hip_runtime.h>
#include <hip/hip_bf16.h>
#include <stdint.h>

// GRU sequence decoder, fused. B=32768, H=L=512, VOCAB=10, SEQ=6.
// R18 = R10 (573us best) + alias-wall fix WITHOUT R17's I-cache blowup.
// R17 lesson: full 6x t-unroll -> ~50KB body -> I-cache thrash (FETCH +27MB,
// dur 691). R18: runtime loop of 3 iterations, each stamping TWO step bodies
// with STATIC hA->hB / hB->hA buffers (code = 2x body ~ 14KB, fits 32KB
// I-cache). Static bases make ds_write(wr) vs ds_read(rd) provably disjoint
// so the scheduler can slide pass p's epilogue under pass p+1's k-loop
// (MFMA and VALU are separate pipes, m114). All else identical to R10:
// 8 waves, wave owns jtiles [wq*4,wq*4+4) x 4 btiles; XOR swizzle
// byte^=(row&7)<<4; gi in ws per-lane frag order w/ pass-head prefetch;
// kk unroll 4; one barrier per step; logits on waves 0-3 post-barrier.
// __launch_bounds__(512,1), NBLK=512, 1 block/CU.

typedef __bf16 bf16_t;
typedef bf16_t bf16x8 __attribute__((ext_vector_type(8)));
typedef bf16_t bf16x4 __attribute__((ext_vector_type(4)));
typedef float  f32x4  __attribute__((ext_vector_type(4)));
typedef float  f32x2  __attribute__((ext_vector_type(2)));

#define THREADS 512
#define BM      64
#define NBLK    512
#define NSTEP   6
#define BUFB    (BM * 1024)

// ws layout (bytes)
#define WIH_OFF 0u            // 96 nt * 16 kk * 64 lane * 16B = 1572864
#define WHH_OFF 1572864u
#define WOP_OFF 3145728u      // 16 kk * 64 lane * 16B = 16384
#define GI_OFF  4194304u      // 512 blk * 24576 chunks * 8B = 100663296

static __device__ __forceinline__ float sigm(float v) { return 1.0f / (1.0f + __expf(-v)); }
static __device__ __forceinline__ float tanhf_(float v) {
  v = fminf(fmaxf(v, -12.0f), 12.0f);
  float e = __expf(2.0f * v);
  return 1.0f - 2.0f / (e + 1.0f);
}
static __device__ __forceinline__ f32x4 up4(bf16x4 v) {
  f32x4 o; o[0] = (float)v[0]; o[1] = (float)v[1]; o[2] = (float)v[2]; o[3] = (float)v[3];
  return o;
}
static __device__ __forceinline__ bf16x4 pk4(f32x4 v) {
  bf16x4 o; o[0] = (bf16_t)v[0]; o[1] = (bf16_t)v[1]; o[2] = (bf16_t)v[2]; o[3] = (bf16_t)v[3];
  return o;
}

// Pack weights into MFMA A-frag order:
//   chunk[(nt*16 + kk)*64 + lane] = w[nt*16 + (lane&15)][kk*32 + (lane>>4)*8 .. +8]
__global__ void prep_kernel(const float* __restrict__ wih_f, const float* __restrict__ whh_f,
                            const float* __restrict__ wout_f,
                            bf16x8* __restrict__ wihPk, bf16x8* __restrict__ whhPk,
                            bf16x8* __restrict__ wopPk) {
  int c = blockIdx.x * 256 + threadIdx.x;
  int lane = c & 63, l15 = lane & 15, lk = (lane >> 4) & 3;
  if (c < 196608) {
    int cid = (c < 98304) ? c : c - 98304;
    const float* src = (c < 98304) ? wih_f : whh_f;
    bf16x8* dst = (c < 98304) ? wihPk : whhPk;
    int kk = (cid >> 6) & 15;
    int nt = cid >> 10;
    const float* p = src + (size_t)(nt * 16 + l15) * 512 + kk * 32 + lk * 8;
    bf16x8 o;
    #pragma unroll
    for (int i = 0; i < 8; ++i) o[i] = (bf16_t)p[i];
    dst[cid] = o;
  } else if (c < 197632) {
    int cid = c - 196608;          // vocab tile: 16 kk * 64 lane
    int kk = cid >> 6;
    bf16x8 o;
    if (l15 < 10) {
      const float* p = wout_f + (size_t)l15 * 512 + kk * 32 + lk * 8;
      #pragma unroll
      for (int i = 0; i < 8; ++i) o[i] = (bf16_t)p[i];
    } else {
      #pragma unroll
      for (int i = 0; i < 8; ++i) o[i] = (bf16_t)0.0f;
    }
    wopPk[cid] = o;
  }
}

// One recurrent step: read RD (h_t), write WR (h_{t+1}), then logits for
// timestep TT from WR. RD/WR are compile-time &hlds[0]/&hlds[BUFB].
#define GRU_STEP(RD, WR, TT)                                                   \
  {                                                                            \
    _Pragma("unroll")                                                          \
    for (int p = 0; p < 4; ++p) {                                              \
      const int jt = wq * 4 + p;                                               \
      const int cb = jt * 12;                                                  \
      bf16x4 gpre[3][4];                                                       \
      _Pragma("unroll")                                                        \
      for (int g = 0; g < 3; ++g)                                              \
        _Pragma("unroll")                                                      \
        for (int bt = 0; bt < 4; ++bt)                                         \
          gpre[g][bt] = gi[gibase + ((size_t)(cb + g * 4 + bt) << 6) + lane];  \
      f32x4 acc[3][4];                                                         \
      _Pragma("unroll")                                                        \
      for (int g = 0; g < 3; ++g)                                              \
        _Pragma("unroll")                                                      \
        for (int bt = 0; bt < 4; ++bt) acc[g][bt] = (f32x4){0.f, 0.f, 0.f, 0.f}; \
      _Pragma("unroll 4")                                                      \
      for (int kk = 0; kk < 16; ++kk) {                                        \
        bf16x8 hf[4];                                                          \
        _Pragma("unroll")                                                      \
        for (int bt = 0; bt < 4; ++bt)                                         \
          hf[bt] = *(const bf16x8*)(&(RD)[(bt * 16 + l15) * 1024 +             \
                                          ((kk * 64) ^ kbase)]);               \
        _Pragma("unroll")                                                      \
        for (int g = 0; g < 3; ++g) {                                          \
          bf16x8 wf = whh[((g * 32 + jt) * 16 + kk) * 64 + lane];              \
          _Pragma("unroll")                                                    \
          for (int bt = 0; bt < 4; ++bt)                                       \
            acc[g][bt] = __builtin_amdgcn_mfma_f32_16x16x32_bf16(              \
                wf, hf[bt], acc[g][bt], 0, 0, 0);                              \
        }                                                                      \
      }                                                                        \
      {                                                                        \
        int j = jt * 16 + lk * 4;                                              \
        f32x4 bn4 = *(const f32x4*)(b_hh + 1024 + j);                          \
        _Pragma("unroll")                                                      \
        for (int bt = 0; bt < 4; ++bt) {                                       \
          f32x4 gr  = up4(gpre[0][bt]);                                        \
          f32x4 gz  = up4(gpre[1][bt]);                                        \
          f32x4 gn  = up4(gpre[2][bt]);                                        \
          f32x4 hov = up4(*(const bf16x4*)(&(RD)[(bt * 16 + l15) * 1024 +      \
                                                 ((jt * 32) ^ cbase)]));       \
          f32x4 hv;                                                            \
          _Pragma("unroll")                                                    \
          for (int r = 0; r < 4; ++r) {                                        \
            float rv = sigm(gr[r] + acc[0][bt][r]);                            \
            float zv = sigm(gz[r] + acc[1][bt][r]);                            \
            float nv = tanhf_(gn[r] + rv * (acc[2][bt][r] + bn4[r]));          \
            hv[r] = zv * (hov[r] - nv) + nv;                                   \
          }                                                                    \
          *(bf16x4*)(&(WR)[(bt * 16 + l15) * 1024 + ((jt * 32) ^ cbase)]) =    \
              pk4(hv);                                                         \
        }                                                                      \
      }                                                                        \
    }                                                                          \
    __syncthreads();                                                           \
    if (wq < 4) {                                                              \
      f32x4 lacc = (f32x4){0.f, 0.f, 0.f, 0.f};                                \
      _Pragma("unroll 4")                                                      \
      for (int kk = 0; kk < 16; ++kk) {                                        \
        bf16x8 hf = *(const bf16x8*)(&(WR)[(wq * 16 + l15) * 1024 +            \
                                           ((kk * 64) ^ kbase)]);              \
        bf16x8 wf = wop[kk * 64 + lane];                                       \
        lacc = __builtin_amdgcn_mfma_f32_16x16x32_bf16(wf, hf, lacc, 0, 0, 0); \
      }                                                                        \
      size_t ob = (size_t)(brow0 + wq * 16 + l15) * 60 + (TT) * 10 + lk * 4;   \
      if (lk < 2) {                                                            \
        f32x2 a = { lacc[0] + b_out[lk * 4 + 0], lacc[1] + b_out[lk * 4 + 1] };\
        f32x2 b = { lacc[2] + b_out[lk * 4 + 2], lacc[3] + b_out[lk * 4 + 3] };\
        *(f32x2*)(out + ob) = a;                                               \
        *(f32x2*)(out + ob + 2) = b;                                           \
      } else if (lk == 2) {                                                    \
        f32x2 a = { lacc[0] + b_out[8], lacc[1] + b_out[9] };                  \
        *(f32x2*)(out + ob) = a;                                               \
      }                                                                        \
    }                                                                          \
  }

__global__ __launch_bounds__(THREADS, 1) void gru_kernel(
    const float* __restrict__ x, const float* __restrict__ b_ih,
    const float* __restrict__ b_hh, const float* __restrict__ b_out,
    const bf16x8* __restrict__ wih, const bf16x8* __restrict__ whh,
    const bf16x8* __restrict__ wop,
    bf16x4* __restrict__ gi, float* __restrict__ out) {
  // Two h tiles: 64 rows x 512 bf16 (row = 1024B); logical col-byte L of
  // row r stored at physical L ^ ((r&7)<<4). hA/hB alternate per step with
  // compile-time bases (alias-disjoint), 2 step bodies per loop iteration.
  __shared__ __align__(16) char hlds[2 * BUFB];
  char* const hA = hlds;
  char* const hB = hlds + BUFB;

  const int tid   = (int)threadIdx.x;
  const int lane  = tid & 63;
  const int wq    = tid >> 6;      // 0..7: wave owns jtiles [wq*4, wq*4+4)
  const int l15   = lane & 15;
  const int lk    = lane >> 4;
  const int brow0 = (int)blockIdx.x * BM;
  const int swz   = (l15 & 7) << 4;
  const int kbase = (lk * 16) ^ swz;        // b128 read col base (XOR with kk*64)
  const int cbase = (lk * 8) ^ swz;         // b64 cell col base (XOR with jt*32)

  // ---------------- phase 0: x -> bf16 -> hA (h0 = x) ----------------
  #pragma unroll
  for (int it = 0; it < 16; ++it) {
    int f4  = it * THREADS + tid;
    int row = f4 >> 7, c4 = f4 & 127;
    float4 v = ((const float4*)(x + (size_t)(brow0 + row) * 512))[c4];
    bf16x4 h4 = { (bf16_t)v.x, (bf16_t)v.y, (bf16_t)v.z, (bf16_t)v.w };
    *(bf16x4*)(&hA[row * 1024 + ((c4 * 8) ^ ((row & 7) << 4))]) = h4;
  }
  __syncthreads();

  const size_t gibase = (size_t)blockIdx.x * 24576;  // bf16x4 chunks per block
  // gi chunk: (jt*12 + g*4 + bt)*64 + lane,  jt = wq*4 + p

  // ---------------- gi phase: gi = x @ w_ih^T + biases ----------------
  #pragma unroll
  for (int p = 0; p < 4; ++p) {
    const int jt = wq * 4 + p;
    f32x4 acc[3][4];
    #pragma unroll
    for (int g = 0; g < 3; ++g)
      #pragma unroll
      for (int bt = 0; bt < 4; ++bt) acc[g][bt] = (f32x4){0.f, 0.f, 0.f, 0.f};

    #pragma unroll 4
    for (int kk = 0; kk < 16; ++kk) {
      bf16x8 hf[4];
      #pragma unroll
      for (int bt = 0; bt < 4; ++bt)
        hf[bt] = *(const bf16x8*)(&hA[(bt * 16 + l15) * 1024 + ((kk * 64) ^ kbase)]);
      #pragma unroll
      for (int g = 0; g < 3; ++g) {
        bf16x8 wf = wih[((g * 32 + jt) * 16 + kk) * 64 + lane];
        #pragma unroll
        for (int bt = 0; bt < 4; ++bt)
          acc[g][bt] = __builtin_amdgcn_mfma_f32_16x16x32_bf16(wf, hf[bt], acc[g][bt], 0, 0, 0);
      }
    }
    {
      int j = jt * 16 + lk * 4;
      f32x4 b0 = *(const f32x4*)(b_ih + j) + *(const f32x4*)(b_hh + j);
      f32x4 b1 = *(const f32x4*)(b_ih + 512 + j) + *(const f32x4*)(b_hh + 512 + j);
      f32x4 b2 = *(const f32x4*)(b_ih + 1024 + j);   // b_hh_n stays separate (x r)
      #pragma unroll
      for (int bt = 0; bt < 4; ++bt) {
        int cb = jt * 12 + bt;
        gi[gibase + ((size_t)(cb + 0) << 6) + lane] = pk4(acc[0][bt] + b0);
        gi[gibase + ((size_t)(cb + 4) << 6) + lane] = pk4(acc[1][bt] + b1);
        gi[gibase + ((size_t)(cb + 8) << 6) + lane] = pk4(acc[2][bt] + b2);
      }
    }
  }
  // (no barrier: hA unchanged; gi is same-lane RAW, HW-ordered)

  // -------- 6 recurrent steps: 3 iterations x 2 static-buffer bodies ------
  for (int tt = 0; tt < NSTEP; tt += 2) {
    GRU_STEP(hA, hB, tt);       // h_t in hA -> h_{t+1} in hB, logits(tt)
    GRU_STEP(hB, hA, tt + 1);   // h_{t+1} in hB -> h_{t+2} in hA, logits(tt+1)
  }
}

extern "C" void kernel_launch(void* const* d_in, const int* in_sizes, int n_in,
                              void* d_out, int out_size, void* d_ws, size_t ws_size,
                              hipStream_t stream) {
  const float* x     = (const float*)d_in[0];
  const float* wih_f = (const float*)d_in[1];
  const float* whh_f = (const float*)d_in[2];
  const float* b_ih  = (const float*)d_in[3];
  const float* b_hh  = (const float*)d_in[4];
  const float* wout  = (const float*)d_in[5];
  const float* b_out = (const float*)d_in[6];

  char* ws = (char*)d_ws;
  bf16x8* wihPk = (bf16x8*)(ws + WIH_OFF);
  bf16x8* whhPk = (bf16x8*)(ws + WHH_OFF);
  bf16x8* wopPk = (bf16x8*)(ws + WOP_OFF);
  bf16x4* gi    = (bf16x4*)(ws + GI_OFF);

  prep_kernel<<<772, 256, 0, stream>>>(wih_f, whh_f, wout, wihPk, whhPk, wopPk);
  gru_kernel<<<NBLK, THREADS, 0, stream>>>(x, b_ih, b_hh, b_out,
                                           wihPk, whhPk, wopPk, gi, (float*)d_out);
}